// Round 7
// baseline (525.714 us; speedup 1.0000x reference)
//
#include <hip/hip_runtime.h>

#define PH  72
#define HSZ 1152
#define XRW 144          // x frag-tile row stride (halves)
#define XSL 584          // per-t-slot stride (4*XRW + 8 pad) halves

typedef float f32x4 __attribute__((ext_vector_type(4)));
typedef _Float16 f16x8 __attribute__((ext_vector_type(8)));

__device__ __forceinline__ float sigmoid_f(float x) {
    float e = __builtin_amdgcn_exp2f(-1.4426950408889634f * x);
    return __builtin_amdgcn_rcpf(1.0f + e);
}
__device__ __forceinline__ float tanh_f(float x) {
    float e = __builtin_amdgcn_exp2f(-2.8853900817779268f * x);
    return 2.0f * __builtin_amdgcn_rcpf(1.0f + e) - 1.0f;
}
__device__ __forceinline__ f16x8 load_frag16h(const float* wp, int n, int K, int k0) {
    const float* wf = wp + (size_t)n * K + k0;
    f16x8 h;
    #pragma unroll
    for (int j = 0; j < 8; ++j) h[j] = (_Float16)wf[j];
    return h;
}
__device__ __forceinline__ void load_frag16(const float* wp, int n, int K, int k0,
                                            f16x8& hi, f16x8& lo) {
    const float* wf = wp + (size_t)n * K + k0;
    #pragma unroll
    for (int j = 0; j < 8; ++j) {
        const float v = wf[j];
        const _Float16 h = (_Float16)v;
        hi[j] = h;
        lo[j] = (_Float16)(v - (float)h);
    }
}
__device__ __forceinline__ void gload16(const void* g, void* l) {
    __builtin_amdgcn_global_load_lds(
        (const __attribute__((address_space(1))) unsigned int*)g,
        (__attribute__((address_space(3))) unsigned int*)l, 16, 0, 0);
}

#define MFMA16(a, b, c) __builtin_amdgcn_mfma_f32_16x16x32_f16(a, b, c, 0, 0, 0)

// ======= fused rec v9: role phase-staggering =======
// 256 blocks x 768 thr (12 waves: 4 L1, 4 L0, 4 proj; one of each per SIMD).
// v8 post-mortem: step time == sum of per-pipe demands (MFMA 960 + VALU 745 +
// LDS ~550 cy) -> pipes run serially because all waves are in the same phase.
// v9 staggers phases:
//  - proj: ax frag reads hoisted PRE-barrier (written >=2 barriers earlier);
//    post-barrier proj issues 16 independent MFMAs immediately (fills matrix
//    pipe during L0/L1's h-read latency). Produces xp THREE steps ahead.
//  - L0: xp read hoisted PRE-barrier (slot written 1 barrier earlier).
//  - setprio(1) around L0/L1 bodies so recurrence chains preempt proj bulk.
// Ring/convert safety: xp slot write-after-read separated by 2 barriers;
// frag convert (chunk c+1 done at step 16c+11) vs pre-read (>=16c+12) ok.
__global__ __launch_bounds__(768, 3) void rec_fused(
    const float* __restrict__ x,
    const float* __restrict__ wih0, const float* __restrict__ whh0,
    const float* __restrict__ bih0, const float* __restrict__ bhh0,
    const float* __restrict__ wih1, const float* __restrict__ whh1,
    const float* __restrict__ bih1, const float* __restrict__ bhh1,
    const float* __restrict__ wfc,  const float* __restrict__ bfc,
    float* __restrict__ out)
{
    __shared__ float    xs32[4 * 2048];          // 32 KB staging strip
    __shared__ _Float16 xh[32 * XSL];            // 37,376 B x frags (f16)
    __shared__ float    xpl[4 * 1024];           // 16 KB xp ring (4 t-slots)
    __shared__ _Float16 h0[2 * HSZ], h1[2 * HSZ];
    const int tid = threadIdx.x, lane = tid & 63, w = tid >> 6;
    const int l16 = lane & 15, quad = lane >> 4, k0 = quad * 8;
    const int wl = w & 3;
    const int role = w >> 2;                     // 0=L1, 1=L0, 2=proj
    const bool is1 = (role == 0), is0 = (role == 1), isP = (role == 2);
    const int bb  = blockIdx.x & 63;
    const int sub = blockIdx.x >> 6;

    const float* xrow = x + (size_t)(bb * 16 + wl * 4 + sub) * 128 * 256;

    f16x8 fA[4][2], fB[4][4];
    float gb[4] = {0.f, 0.f, 0.f, 0.f};
    #pragma unroll
    for (int g = 0; g < 4; ++g) {
        const int n = g * 64 + wl * 16 + l16;
        if (is1) {
            #pragma unroll
            for (int ks = 0; ks < 2; ++ks) {
                fA[g][ks] = load_frag16h(wih1, n, 64, ks * 32 + k0);
                load_frag16(whh1, n, 64, ks * 32 + k0, fB[g][ks], fB[g][2 + ks]);
            }
            gb[g] = bih1[n] + bhh1[n];
        } else if (is0) {
            #pragma unroll
            for (int ks = 0; ks < 2; ++ks)
                load_frag16(whh0, n, 64, ks * 32 + k0, fA[g][ks], fB[g][2 + ks]);
        } else {
            #pragma unroll
            for (int ks = 0; ks < 4; ++ks)
                fB[g][ks] = load_frag16h(wih0, n, 128, ks * 32 + k0);
            gb[g] = bih0[n] + bhh0[n];
        }
    }
    for (int i = tid; i < 2 * HSZ; i += 768) { h0[i] = (_Float16)0.f; h1[i] = (_Float16)0.f; }
    float c = 0.f;       // lane's cell state (c1 for L1, c0 for L0)
    f32x4 xpr;           // L0: pre-read xp for the upcoming step
    f16x8 axr[4];        // proj: pre-read x frags for the upcoming tp

    // ---- proj-wave helpers ----
    auto convert_rows = [&](int cc, int ib0, int nib) {
        const int sb = (cc & 1) * 16;
        const int tq = lane & 3;
        for (int ib = ib0; ib < ib0 + nib; ++ib) {
            const float4 v = *(const float4*)&xs32[wl * 2048 + ib * 256 + lane * 4];
            const int d = ib * 16 + (lane >> 2);
            const float vv[4] = {v.x, v.y, v.z, v.w};
            #pragma unroll
            for (int j = 0; j < 4; ++j)
                xh[(sb + tq * 4 + j) * XSL + wl * XRW + d] = (_Float16)vv[j];
        }
    };
    auto issue_chunk = [&](int cc) {
        #pragma unroll
        for (int ib = 0; ib < 8; ++ib)
            gload16(xrow + (size_t)(ib * 16 + (lane >> 2)) * 256 + cc * 16 + (lane & 3) * 4,
                    (char*)xs32 + wl * 8192 + ib * 1024);
    };
    // self-reading xp producer (prologue only)
    auto compute_xp = [&](int tp) {
        const int fs = ((tp >> 4) & 1) * 16 + (tp & 15);
        f16x8 ax[4];
        #pragma unroll
        for (int ks = 0; ks < 4; ++ks)
            ax[ks] = *(const f16x8*)&xh[fs * XSL + (l16 >> 2) * XRW + ks * 32 + k0];
        f32x4 pa[4];
        #pragma unroll
        for (int g = 0; g < 4; ++g) pa[g] = (f32x4){gb[g], 0.f, 0.f, 0.f};
        #pragma unroll
        for (int g = 0; g < 4; ++g)
            #pragma unroll
            for (int ks = 0; ks < 4; ++ks)
                pa[g] = MFMA16(ax[ks], fB[g][ks], pa[g]);
        f32x4 o;
        o[0] = pa[0][0]; o[1] = pa[1][0]; o[2] = pa[2][0]; o[3] = pa[3][0];
        *(f32x4*)&xpl[(((tp & 3) * 4 + wl) * 64 + lane) * 4] = o;
    };

    if (isP) issue_chunk(0);
    __syncthreads();                 // chunk0 drained; h zeroed
    if (isP) { convert_rows(0, 0, 8); issue_chunk(1); }
    __syncthreads();                 // xh chunk0 visible; chunk1 drained
    if (isP) { compute_xp(0); compute_xp(1); compute_xp(2); }
    __syncthreads();                 // xp[0..2] visible
    if (is0) {                       // prologue: layer0 t=0 (h=0)
        xpr = *(const f32x4*)&xpl[(wl * 64 + lane) * 4];
        const float gi = sigmoid_f(xpr[0]);
        const float gg = tanh_f(xpr[2]);
        const float go = sigmoid_f(xpr[3]);
        c = gi * gg;
        h0[(quad * 4) * PH + wl * 16 + l16] = (_Float16)(go * tanh_f(c));
        xpr = *(const f32x4*)&xpl[((1 * 4 + wl) * 64 + lane) * 4];   // for tn=1
    }
    if (isP) {                       // pre-read ax for tp=3 (chunk 0)
        #pragma unroll
        for (int ks = 0; ks < 4; ++ks)
            axr[ks] = *(const f16x8*)&xh[3 * XSL + (l16 >> 2) * XRW + ks * 32 + k0];
    }
    __syncthreads();

    for (int t = 0; t < 255; ++t) {
        const int s0 = t & 1, s1 = s0 ^ 1;
        const int tn = t + 1;
        if (is1) {
            __builtin_amdgcn_s_setprio(1);
            f16x8 ah[2], bh[2];
            #pragma unroll
            for (int ks = 0; ks < 2; ++ks) {
                ah[ks] = *(const f16x8*)&h0[s0 * HSZ + l16 * PH + ks * 32 + k0];
                bh[ks] = *(const f16x8*)&h1[s1 * HSZ + l16 * PH + ks * 32 + k0];
            }
            f32x4 accA[4], accB[4];
            #pragma unroll
            for (int g = 0; g < 4; ++g) {
                accA[g] = (f32x4){gb[g], 0.f, 0.f, 0.f};
                accB[g] = (f32x4){0.f, 0.f, 0.f, 0.f};
            }
            #pragma unroll
            for (int g = 0; g < 4; ++g)
                #pragma unroll
                for (int ks = 0; ks < 2; ++ks) {
                    accA[g] = MFMA16(ah[ks], fA[g][ks], accA[g]);
                    accA[g] = MFMA16(bh[ks], fB[g][ks], accA[g]);
                    accB[g] = MFMA16(bh[ks], fB[g][2 + ks], accB[g]);
                }
            const float gi = sigmoid_f(accA[0][0] + accB[0][0]);
            const float gf = sigmoid_f(accA[1][0] + accB[1][0]);
            const float gg = tanh_f(accA[2][0] + accB[2][0]);
            const float go = sigmoid_f(accA[3][0] + accB[3][0]);
            c = gf * c + gi * gg;
            h1[s0 * HSZ + (quad * 4) * PH + wl * 16 + l16] =
                (_Float16)(go * tanh_f(c));
            __builtin_amdgcn_s_setprio(0);
        } else if (is0) {
            __builtin_amdgcn_s_setprio(1);
            f16x8 ah[2];
            #pragma unroll
            for (int ks = 0; ks < 2; ++ks)
                ah[ks] = *(const f16x8*)&h0[s0 * HSZ + l16 * PH + ks * 32 + k0];
            f32x4 accA[4], accB[4];
            #pragma unroll
            for (int g = 0; g < 4; ++g) {
                accA[g] = (f32x4){xpr[g], 0.f, 0.f, 0.f};
                accB[g] = (f32x4){0.f, 0.f, 0.f, 0.f};
            }
            #pragma unroll
            for (int g = 0; g < 4; ++g)
                #pragma unroll
                for (int ks = 0; ks < 2; ++ks) {
                    accA[g] = MFMA16(ah[ks], fA[g][ks], accA[g]);
                    accB[g] = MFMA16(ah[ks], fB[g][2 + ks], accB[g]);
                }
            const float gi = sigmoid_f(accA[0][0] + accB[0][0]);
            const float gf = sigmoid_f(accA[1][0] + accB[1][0]);
            const float gg = tanh_f(accA[2][0] + accB[2][0]);
            const float go = sigmoid_f(accA[3][0] + accB[3][0]);
            c = gf * c + gi * gg;
            h0[s1 * HSZ + (quad * 4) * PH + wl * 16 + l16] =
                (_Float16)(go * tanh_f(c));
            __builtin_amdgcn_s_setprio(0);
            if (tn < 255) {                       // pre-read xp for step tn+1
                const int tq = tn + 1;            // written by proj >=1 barrier ago
                xpr = *(const f32x4*)&xpl[(((tq & 3) * 4 + wl) * 64 + lane) * 4];
            }
        } else {
            // post-barrier: produce xp[t+3] from PRE-READ axr — MFMAs issue
            // immediately (no LDS read dependency), filling the matrix pipe
            // while L0/L1 wait on their h reads.
            const int tp = t + 3;
            if (tp <= 255) {
                f32x4 pa[4];
                #pragma unroll
                for (int g = 0; g < 4; ++g) pa[g] = (f32x4){gb[g], 0.f, 0.f, 0.f};
                #pragma unroll
                for (int g = 0; g < 4; ++g)
                    #pragma unroll
                    for (int ks = 0; ks < 4; ++ks)
                        pa[g] = MFMA16(axr[ks], fB[g][ks], pa[g]);
                f32x4 o;
                o[0] = pa[0][0]; o[1] = pa[1][0]; o[2] = pa[2][0]; o[3] = pa[3][0];
                *(f32x4*)&xpl[(((tp & 3) * 4 + wl) * 64 + lane) * 4] = o;
            }
            if ((tn & 15) == 0 && tn < 240)         // issue next chunk (DMA)
                issue_chunk((tn >> 4) + 1);
            const int m16 = tn & 15;
            if (m16 >= 8 && m16 < 12 && tn < 248)   // spread strip->frag convert
                convert_rows((tn >> 4) + 1, (m16 - 8) * 2, 2);
            const int tpn = t + 4;                  // pre-read ax for next iter
            if (tpn <= 255) {
                const int fs = ((tpn >> 4) & 1) * 16 + (tpn & 15);
                #pragma unroll
                for (int ks = 0; ks < 4; ++ks)
                    axr[ks] = *(const f16x8*)&xh[fs * XSL + (l16 >> 2) * XRW + ks * 32 + k0];
            }
        }
        __syncthreads();
    }

    if (is1) {   // epilogue: layer1[255] (h0 slot1, h1 slot0 -> h1 slot1)
        f16x8 ah[2], bh[2];
        #pragma unroll
        for (int ks = 0; ks < 2; ++ks) {
            ah[ks] = *(const f16x8*)&h0[HSZ + l16 * PH + ks * 32 + k0];
            bh[ks] = *(const f16x8*)&h1[l16 * PH + ks * 32 + k0];
        }
        f32x4 accA[4], accB[4];
        #pragma unroll
        for (int g = 0; g < 4; ++g) {
            accA[g] = (f32x4){gb[g], 0.f, 0.f, 0.f};
            accB[g] = (f32x4){0.f, 0.f, 0.f, 0.f};
        }
        #pragma unroll
        for (int g = 0; g < 4; ++g)
            #pragma unroll
            for (int ks = 0; ks < 2; ++ks) {
                accA[g] = MFMA16(ah[ks], fA[g][ks], accA[g]);
                accA[g] = MFMA16(bh[ks], fB[g][ks], accA[g]);
                accB[g] = MFMA16(bh[ks], fB[g][2 + ks], accB[g]);
            }
        const float gi = sigmoid_f(accA[0][0] + accB[0][0]);
        const float gf = sigmoid_f(accA[1][0] + accB[1][0]);
        const float gg = tanh_f(accA[2][0] + accB[2][0]);
        const float go = sigmoid_f(accA[3][0] + accB[3][0]);
        c = gf * c + gi * gg;
        h1[HSZ + (quad * 4) * PH + wl * 16 + l16] = (_Float16)(go * tanh_f(c));
    }
    __syncthreads();

    // head: row m = sel*4 (slot 1); out row = bb*16 + sel*4 + sub
    if (tid < 512) {
        const int n   = tid & 127;
        const int sel = tid >> 7;
        float s = 0.f;
        for (int k = 0; k < 64; ++k)
            s += (float)h1[HSZ + (sel * 4) * PH + k] * wfc[n * 64 + k];
        out[(size_t)(bb * 16 + sel * 4 + sub) * 128 + n] = s + bfc[n];
    }
}

extern "C" void kernel_launch(void* const* d_in, const int* in_sizes, int n_in,
                              void* d_out, int out_size, void* d_ws, size_t ws_size,
                              hipStream_t stream) {
    const float* x     = (const float*)d_in[0];
    const float* wih0  = (const float*)d_in[1];
    const float* whh0  = (const float*)d_in[2];
    const float* bih0  = (const float*)d_in[3];
    const float* bhh0  = (const float*)d_in[4];
    const float* wih1  = (const float*)d_in[5];
    const float* whh1  = (const float*)d_in[6];
    const float* bih1  = (const float*)d_in[7];
    const float* bhh1  = (const float*)d_in[8];
    const float* wfc   = (const float*)d_in[9];
    const float* bfc   = (const float*)d_in[10];
    float* out = (float*)d_out;

    rec_fused<<<256, 768, 0, stream>>>(x, wih0, whh0, bih0, bhh0,
                                       wih1, whh1, bih1, bhh1, wfc, bfc, out);
}

// Round 8
// 521.616 us; speedup vs baseline: 1.0079x; 1.0079x over previous
//
#include <hip/hip_runtime.h>

#define PH  72
#define HSZ 1152
#define XRW 144          // x frag-tile row stride (halves)
#define XSL 584          // per-t-slot stride (4*XRW + 8 pad) halves

typedef float f32x4 __attribute__((ext_vector_type(4)));
typedef _Float16 f16x8 __attribute__((ext_vector_type(8)));

__device__ __forceinline__ float sigmoid_f(float x) {
    float e = __builtin_amdgcn_exp2f(-1.4426950408889634f * x);
    return __builtin_amdgcn_rcpf(1.0f + e);
}
__device__ __forceinline__ float tanh_f(float x) {
    float e = __builtin_amdgcn_exp2f(-2.8853900817779268f * x);
    return 2.0f * __builtin_amdgcn_rcpf(1.0f + e) - 1.0f;
}
__device__ __forceinline__ f16x8 load_frag16h(const float* wp, int n, int K, int k0) {
    const float* wf = wp + (size_t)n * K + k0;
    f16x8 h;
    #pragma unroll
    for (int j = 0; j < 8; ++j) h[j] = (_Float16)wf[j];
    return h;
}
__device__ __forceinline__ void load_frag16(const float* wp, int n, int K, int k0,
                                            f16x8& hi, f16x8& lo) {
    const float* wf = wp + (size_t)n * K + k0;
    #pragma unroll
    for (int j = 0; j < 8; ++j) {
        const float v = wf[j];
        const _Float16 h = (_Float16)v;
        hi[j] = h;
        lo[j] = (_Float16)(v - (float)h);
    }
}
__device__ __forceinline__ void gload16(const void* g, void* l) {
    __builtin_amdgcn_global_load_lds(
        (const __attribute__((address_space(1))) unsigned int*)g,
        (__attribute__((address_space(3))) unsigned int*)l, 16, 0, 0);
}

#define MFMA16(a, b, c) __builtin_amdgcn_mfma_f32_16x16x32_f16(a, b, c, 0, 0, 0)

// ======= fused rec v10: v8 base + 4-timestep-packed proj MFMA =======
// 256 blocks x 768 thr (12 waves: 4 L1, 4 L0, 4 proj; one of each per SIMD).
// v9 post-mortem: live-across-barrier regs (axr/xpr) + setprio -> scratch
// (WRITE 13.6MB), 404us. Reverted to v8 structure (no live state, no setprio).
// v10 change: proj's 16x16 MFMA M-rows were 4x redundant (only reg 0 of each
// acc consumed). Pack FOUR timesteps into the M dimension:
//   A-row m = 4q+r  <->  x[staged row q][timestep tpb+r]
//   output row quad*4+reg <-> timestep tpb+reg  (C/D row=(lane>>4)*4+reg)
// One 16-MFMA batch -> xp for 4 timesteps; proj batches every 4th step.
// Per-CU MFMA/step: 224 -> 176 (-21%); proj frag-reads /4. xp ring: 8 slots.
// Batch at t%4==0 writes slots (t+4..t+7)&7; L0 reads slot (t+1)&7 ->
// write-to-read 3 barriers, overwrite 5 barriers. Convert window moved to
// tn%16 in {2,3,6,7} (disjoint from batch steps t%16 in {0,4,8,12}).
__global__ __launch_bounds__(768, 3) void rec_fused(
    const float* __restrict__ x,
    const float* __restrict__ wih0, const float* __restrict__ whh0,
    const float* __restrict__ bih0, const float* __restrict__ bhh0,
    const float* __restrict__ wih1, const float* __restrict__ whh1,
    const float* __restrict__ bih1, const float* __restrict__ bhh1,
    const float* __restrict__ wfc,  const float* __restrict__ bfc,
    float* __restrict__ out)
{
    __shared__ float    xs32[4 * 2048];          // 32 KB staging strip
    __shared__ _Float16 xh[32 * XSL];            // 37,376 B x frags (f16)
    __shared__ float    xpl[8 * 1024];           // 32 KB xp ring (8 t-slots)
    __shared__ _Float16 h0[2 * HSZ], h1[2 * HSZ];
    const int tid = threadIdx.x, lane = tid & 63, w = tid >> 6;
    const int l16 = lane & 15, quad = lane >> 4, k0 = quad * 8;
    const int wl = w & 3;
    const int role = w >> 2;                     // 0=L1, 1=L0, 2=proj
    const bool is1 = (role == 0), is0 = (role == 1), isP = (role == 2);
    const int bb  = blockIdx.x & 63;
    const int sub = blockIdx.x >> 6;

    const float* xrow = x + (size_t)(bb * 16 + wl * 4 + sub) * 128 * 256;

    f16x8 fA[4][2], fB[4][4];
    float gb[4] = {0.f, 0.f, 0.f, 0.f};
    #pragma unroll
    for (int g = 0; g < 4; ++g) {
        const int n = g * 64 + wl * 16 + l16;
        if (is1) {
            #pragma unroll
            for (int ks = 0; ks < 2; ++ks) {
                fA[g][ks] = load_frag16h(wih1, n, 64, ks * 32 + k0);
                load_frag16(whh1, n, 64, ks * 32 + k0, fB[g][ks], fB[g][2 + ks]);
            }
            gb[g] = bih1[n] + bhh1[n];
        } else if (is0) {
            #pragma unroll
            for (int ks = 0; ks < 2; ++ks)
                load_frag16(whh0, n, 64, ks * 32 + k0, fA[g][ks], fB[g][2 + ks]);
        } else {
            #pragma unroll
            for (int ks = 0; ks < 4; ++ks)
                fB[g][ks] = load_frag16h(wih0, n, 128, ks * 32 + k0);
            gb[g] = bih0[n] + bhh0[n];
        }
    }
    for (int i = tid; i < 2 * HSZ; i += 768) { h0[i] = (_Float16)0.f; h1[i] = (_Float16)0.f; }
    float c = 0.f;       // lane's cell state (c1 for L1, c0 for L0)

    // ---- proj-wave helpers ----
    auto convert_rows = [&](int cc, int ib0, int nib) {
        const int sb = (cc & 1) * 16;
        const int tq = lane & 3;
        for (int ib = ib0; ib < ib0 + nib; ++ib) {
            const float4 v = *(const float4*)&xs32[wl * 2048 + ib * 256 + lane * 4];
            const int d = ib * 16 + (lane >> 2);
            const float vv[4] = {v.x, v.y, v.z, v.w};
            #pragma unroll
            for (int j = 0; j < 4; ++j)
                xh[(sb + tq * 4 + j) * XSL + wl * XRW + d] = (_Float16)vv[j];
        }
    };
    auto issue_chunk = [&](int cc) {
        #pragma unroll
        for (int ib = 0; ib < 8; ++ib)
            gload16(xrow + (size_t)(ib * 16 + (lane >> 2)) * 256 + cc * 16 + (lane & 3) * 4,
                    (char*)xs32 + wl * 8192 + ib * 1024);
    };
    // 4-timestep-packed xp batch: tpb % 4 == 0; produces xp[tpb .. tpb+3].
    // A-row m = lane's l16: staged row l16>>2, timestep tpb + (l16&3).
    auto compute_xp4 = [&](int tpb) {
        const int tpl = tpb + (l16 & 3);                 // this lane's timestep
        const int fs  = ((tpl >> 4) & 1) * 16 + (tpl & 15);
        f16x8 ax[4];
        #pragma unroll
        for (int ks = 0; ks < 4; ++ks)
            ax[ks] = *(const f16x8*)&xh[fs * XSL + (l16 >> 2) * XRW + ks * 32 + k0];
        f32x4 pa[4];
        #pragma unroll
        for (int g = 0; g < 4; ++g) pa[g] = (f32x4){gb[g], gb[g], gb[g], gb[g]};
        #pragma unroll
        for (int g = 0; g < 4; ++g)
            #pragma unroll
            for (int ks = 0; ks < 4; ++ks)
                pa[g] = MFMA16(ax[ks], fB[g][ks], pa[g]);
        #pragma unroll
        for (int r = 0; r < 4; ++r) {                    // reg r = timestep tpb+r
            f32x4 o;
            o[0] = pa[0][r]; o[1] = pa[1][r]; o[2] = pa[2][r]; o[3] = pa[3][r];
            *(f32x4*)&xpl[((((tpb + r) & 7) * 4 + wl) * 64 + lane) * 4] = o;
        }
    };

    if (isP) issue_chunk(0);
    __syncthreads();                 // chunk0 drained; h zeroed
    if (isP) { convert_rows(0, 0, 8); issue_chunk(1); }
    __syncthreads();                 // xh chunk0 visible; chunk1 drained
    if (isP) compute_xp4(0);         // xp[0..3]
    __syncthreads();                 // xp[0..3] visible
    if (is0) {                       // prologue: layer0 t=0 (h=0)
        const f32x4 xp4 = *(const f32x4*)&xpl[(wl * 64 + lane) * 4];
        const float gi = sigmoid_f(xp4[0]);
        const float gg = tanh_f(xp4[2]);
        const float go = sigmoid_f(xp4[3]);
        c = gi * gg;
        h0[(quad * 4) * PH + wl * 16 + l16] = (_Float16)(go * tanh_f(c));
    }
    __syncthreads();

    for (int t = 0; t < 255; ++t) {
        const int s0 = t & 1, s1 = s0 ^ 1;
        const int tn = t + 1;
        if (is1) {
            f16x8 ah[2], bh[2];
            #pragma unroll
            for (int ks = 0; ks < 2; ++ks) {
                ah[ks] = *(const f16x8*)&h0[s0 * HSZ + l16 * PH + ks * 32 + k0];
                bh[ks] = *(const f16x8*)&h1[s1 * HSZ + l16 * PH + ks * 32 + k0];
            }
            f32x4 accA[4], accB[4];
            #pragma unroll
            for (int g = 0; g < 4; ++g) {
                accA[g] = (f32x4){gb[g], 0.f, 0.f, 0.f};
                accB[g] = (f32x4){0.f, 0.f, 0.f, 0.f};
            }
            #pragma unroll
            for (int g = 0; g < 4; ++g)
                #pragma unroll
                for (int ks = 0; ks < 2; ++ks) {
                    accA[g] = MFMA16(ah[ks], fA[g][ks], accA[g]);
                    accA[g] = MFMA16(bh[ks], fB[g][ks], accA[g]);
                    accB[g] = MFMA16(bh[ks], fB[g][2 + ks], accB[g]);
                }
            const float gi = sigmoid_f(accA[0][0] + accB[0][0]);
            const float gf = sigmoid_f(accA[1][0] + accB[1][0]);
            const float gg = tanh_f(accA[2][0] + accB[2][0]);
            const float go = sigmoid_f(accA[3][0] + accB[3][0]);
            c = gf * c + gi * gg;
            h1[s0 * HSZ + (quad * 4) * PH + wl * 16 + l16] =
                (_Float16)(go * tanh_f(c));
        } else if (is0) {
            const f32x4 xp4 =
                *(const f32x4*)&xpl[(((tn & 7) * 4 + wl) * 64 + lane) * 4];
            f16x8 ah[2];
            #pragma unroll
            for (int ks = 0; ks < 2; ++ks)
                ah[ks] = *(const f16x8*)&h0[s0 * HSZ + l16 * PH + ks * 32 + k0];
            f32x4 accA[4], accB[4];
            #pragma unroll
            for (int g = 0; g < 4; ++g) {
                accA[g] = (f32x4){xp4[g], 0.f, 0.f, 0.f};
                accB[g] = (f32x4){0.f, 0.f, 0.f, 0.f};
            }
            #pragma unroll
            for (int g = 0; g < 4; ++g)
                #pragma unroll
                for (int ks = 0; ks < 2; ++ks) {
                    accA[g] = MFMA16(ah[ks], fA[g][ks], accA[g]);
                    accB[g] = MFMA16(ah[ks], fB[g][2 + ks], accB[g]);
                }
            const float gi = sigmoid_f(accA[0][0] + accB[0][0]);
            const float gf = sigmoid_f(accA[1][0] + accB[1][0]);
            const float gg = tanh_f(accA[2][0] + accB[2][0]);
            const float go = sigmoid_f(accA[3][0] + accB[3][0]);
            c = gf * c + gi * gg;
            h0[s1 * HSZ + (quad * 4) * PH + wl * 16 + l16] =
                (_Float16)(go * tanh_f(c));
        } else {
            if ((t & 3) == 0 && t + 4 <= 255)       // 4-timestep xp batch
                compute_xp4(t + 4);
            if ((tn & 15) == 0 && tn < 240)         // issue next chunk (DMA)
                issue_chunk((tn >> 4) + 1);
            const int m16 = tn & 15;                // convert: tn%16 in {2,3,6,7}
            if ((m16 == 2 || m16 == 3 || m16 == 6 || m16 == 7) && tn < 240) {
                const int ib0 = (m16 >= 6 ? (m16 - 6) + 2 : (m16 - 2)) * 2;
                convert_rows((tn >> 4) + 1, ib0, 2);
            }
        }
        __syncthreads();
    }

    if (is1) {   // epilogue: layer1[255] (h0 slot1, h1 slot0 -> h1 slot1)
        f16x8 ah[2], bh[2];
        #pragma unroll
        for (int ks = 0; ks < 2; ++ks) {
            ah[ks] = *(const f16x8*)&h0[HSZ + l16 * PH + ks * 32 + k0];
            bh[ks] = *(const f16x8*)&h1[l16 * PH + ks * 32 + k0];
        }
        f32x4 accA[4], accB[4];
        #pragma unroll
        for (int g = 0; g < 4; ++g) {
            accA[g] = (f32x4){gb[g], 0.f, 0.f, 0.f};
            accB[g] = (f32x4){0.f, 0.f, 0.f, 0.f};
        }
        #pragma unroll
        for (int g = 0; g < 4; ++g)
            #pragma unroll
            for (int ks = 0; ks < 2; ++ks) {
                accA[g] = MFMA16(ah[ks], fA[g][ks], accA[g]);
                accA[g] = MFMA16(bh[ks], fB[g][ks], accA[g]);
                accB[g] = MFMA16(bh[ks], fB[g][2 + ks], accB[g]);
            }
        const float gi = sigmoid_f(accA[0][0] + accB[0][0]);
        const float gf = sigmoid_f(accA[1][0] + accB[1][0]);
        const float gg = tanh_f(accA[2][0] + accB[2][0]);
        const float go = sigmoid_f(accA[3][0] + accB[3][0]);
        c = gf * c + gi * gg;
        h1[HSZ + (quad * 4) * PH + wl * 16 + l16] = (_Float16)(go * tanh_f(c));
    }
    __syncthreads();

    // head: row m = sel*4 (slot 1); out row = bb*16 + sel*4 + sub
    if (tid < 512) {
        const int n   = tid & 127;
        const int sel = tid >> 7;
        float s = 0.f;
        for (int k = 0; k < 64; ++k)
            s += (float)h1[HSZ + (sel * 4) * PH + k] * wfc[n * 64 + k];
        out[(size_t)(bb * 16 + sel * 4 + sub) * 128 + n] = s + bfc[n];
    }
}

extern "C" void kernel_launch(void* const* d_in, const int* in_sizes, int n_in,
                              void* d_out, int out_size, void* d_ws, size_t ws_size,
                              hipStream_t stream) {
    const float* x     = (const float*)d_in[0];
    const float* wih0  = (const float*)d_in[1];
    const float* whh0  = (const float*)d_in[2];
    const float* bih0  = (const float*)d_in[3];
    const float* bhh0  = (const float*)d_in[4];
    const float* wih1  = (const float*)d_in[5];
    const float* whh1  = (const float*)d_in[6];
    const float* bih1  = (const float*)d_in[7];
    const float* bhh1  = (const float*)d_in[8];
    const float* wfc   = (const float*)d_in[9];
    const float* bfc   = (const float*)d_in[10];
    float* out = (float*)d_out;

    rec_fused<<<256, 768, 0, stream>>>(x, wih0, whh0, bih0, bhh0,
                                       wih1, whh1, bih1, bhh1, wfc, bfc, out);
}

// Round 9
// 348.770 us; speedup vs baseline: 1.5073x; 1.4956x over previous
//
#include <hip/hip_runtime.h>

#define PH  72
#define HSZ 1152
#define XRW 144          // x frag-tile row stride (halves)
#define XSL 584          // per-t-slot stride (4*XRW + 8 pad) halves

typedef float f32x4 __attribute__((ext_vector_type(4)));
typedef _Float16 f16x8 __attribute__((ext_vector_type(8)));

__device__ __forceinline__ float sigmoid_f(float x) {
    float e = __builtin_amdgcn_exp2f(-1.4426950408889634f * x);
    return __builtin_amdgcn_rcpf(1.0f + e);
}
__device__ __forceinline__ float tanh_f(float x) {
    float e = __builtin_amdgcn_exp2f(-2.8853900817779268f * x);
    return 2.0f * __builtin_amdgcn_rcpf(1.0f + e) - 1.0f;
}
__device__ __forceinline__ f16x8 load_frag16h(const float* wp, int n, int K, int k0) {
    const float* wf = wp + (size_t)n * K + k0;
    f16x8 h;
    #pragma unroll
    for (int j = 0; j < 8; ++j) h[j] = (_Float16)wf[j];
    return h;
}
__device__ __forceinline__ void gload16(const void* g, void* l) {
    __builtin_amdgcn_global_load_lds(
        (const __attribute__((address_space(1))) unsigned int*)g,
        (__attribute__((address_space(3))) unsigned int*)l, 16, 0, 0);
}

#define MFMA16(a, b, c) __builtin_amdgcn_mfma_f32_16x16x32_f16(a, b, c, 0, 0, 0)

// ======= fused rec v11: v8 skeleton + hi/lo-h M-row packing =======
// 256 blocks x 768 thr (12 waves: 4 L1, 4 L0, 4 proj; one of each per SIMD).
// v9/v10 post-mortem: any added per-role transient state -> scratch (WRITE
// 13-19 MB) and 1.7x regression. v8 is the proven-clean skeleton; v11 keeps
// it EXACTLY and only removes work/pressure.
// Precision split moved from weights (B, 2x MFMAs) to h (A, free M-rows):
//   h stored as TWO f16 LDS rows: row 4q = h_hi, row 4q+1 = h_lo (residual).
//   Single-plane f16 weight MFMA -> acc reg0 = sum(h_hi*W), reg1 = sum(h_lo*W)
//   (M-rows independent; C/D row = quad*4 + reg). gate = acc[0] + acc[1].
// MFMA/SIMD/step: L1 24->16, L0 16->8, proj 16  => 56 -> 40 (-29%).
// Registers freed: L1 loses accB + fB[2..3] use; L0 uses fA only.
// Same error order as weight-split (one f16-quantized factor per product);
// L1's wih1*h0 additionally gains the h0_lo correction it lacked.
__global__ __launch_bounds__(768, 3) void rec_fused(
    const float* __restrict__ x,
    const float* __restrict__ wih0, const float* __restrict__ whh0,
    const float* __restrict__ bih0, const float* __restrict__ bhh0,
    const float* __restrict__ wih1, const float* __restrict__ whh1,
    const float* __restrict__ bih1, const float* __restrict__ bhh1,
    const float* __restrict__ wfc,  const float* __restrict__ bfc,
    float* __restrict__ out)
{
    __shared__ float    xs32[4 * 2048];          // 32 KB staging strip
    __shared__ _Float16 xh[32 * XSL];            // 37,376 B x frags (f16)
    __shared__ float    xpl[4 * 1024];           // 16 KB xp ring (4 t-slots)
    __shared__ _Float16 h0[2 * HSZ], h1[2 * HSZ];
    const int tid = threadIdx.x, lane = tid & 63, w = tid >> 6;
    const int l16 = lane & 15, quad = lane >> 4, k0 = quad * 8;
    const int wl = w & 3;
    const int role = w >> 2;                     // 0=L1, 1=L0, 2=proj
    const bool is1 = (role == 0), is0 = (role == 1), isP = (role == 2);
    const int bb  = blockIdx.x & 63;
    const int sub = blockIdx.x >> 6;

    const float* xrow = x + (size_t)(bb * 16 + wl * 4 + sub) * 128 * 256;

    f16x8 fA[4][2], fB[4][4];
    float gb[4] = {0.f, 0.f, 0.f, 0.f};
    #pragma unroll
    for (int g = 0; g < 4; ++g) {
        const int n = g * 64 + wl * 16 + l16;
        if (is1) {
            #pragma unroll
            for (int ks = 0; ks < 2; ++ks) {
                fA[g][ks] = load_frag16h(wih1, n, 64, ks * 32 + k0);
                fB[g][ks] = load_frag16h(whh1, n, 64, ks * 32 + k0);
            }
            gb[g] = bih1[n] + bhh1[n];
        } else if (is0) {
            #pragma unroll
            for (int ks = 0; ks < 2; ++ks)
                fA[g][ks] = load_frag16h(whh0, n, 64, ks * 32 + k0);
        } else {
            #pragma unroll
            for (int ks = 0; ks < 4; ++ks)
                fB[g][ks] = load_frag16h(wih0, n, 128, ks * 32 + k0);
            gb[g] = bih0[n] + bhh0[n];
        }
    }
    for (int i = tid; i < 2 * HSZ; i += 768) { h0[i] = (_Float16)0.f; h1[i] = (_Float16)0.f; }
    float c = 0.f;       // lane's cell state (c1 for L1, c0 for L0)

    // ---- proj-wave helpers (byte-identical to v8) ----
    auto convert_rows = [&](int cc, int ib0, int nib) {
        const int sb = (cc & 1) * 16;
        const int tq = lane & 3;
        for (int ib = ib0; ib < ib0 + nib; ++ib) {
            const float4 v = *(const float4*)&xs32[wl * 2048 + ib * 256 + lane * 4];
            const int d = ib * 16 + (lane >> 2);
            const float vv[4] = {v.x, v.y, v.z, v.w};
            #pragma unroll
            for (int j = 0; j < 4; ++j)
                xh[(sb + tq * 4 + j) * XSL + wl * XRW + d] = (_Float16)vv[j];
        }
    };
    auto issue_chunk = [&](int cc) {
        #pragma unroll
        for (int ib = 0; ib < 8; ++ib)
            gload16(xrow + (size_t)(ib * 16 + (lane >> 2)) * 256 + cc * 16 + (lane & 3) * 4,
                    (char*)xs32 + wl * 8192 + ib * 1024);
    };
    auto compute_xp = [&](int tp) {
        const int fs = ((tp >> 4) & 1) * 16 + (tp & 15);
        f16x8 ax[4];
        #pragma unroll
        for (int ks = 0; ks < 4; ++ks)
            ax[ks] = *(const f16x8*)&xh[fs * XSL + (l16 >> 2) * XRW + ks * 32 + k0];
        f32x4 pa[4];
        #pragma unroll
        for (int g = 0; g < 4; ++g) pa[g] = (f32x4){gb[g], 0.f, 0.f, 0.f};
        #pragma unroll
        for (int g = 0; g < 4; ++g)
            #pragma unroll
            for (int ks = 0; ks < 4; ++ks)
                pa[g] = MFMA16(ax[ks], fB[g][ks], pa[g]);
        f32x4 o;
        o[0] = pa[0][0]; o[1] = pa[1][0]; o[2] = pa[2][0]; o[3] = pa[3][0];
        *(f32x4*)&xpl[(((tp & 3) * 4 + wl) * 64 + lane) * 4] = o;
    };
    // hi/lo h store: row quad*4 = hi, row quad*4+1 = residual
    auto store_h = [&](_Float16* hbuf, int slot, float hv) {
        const _Float16 hh = (_Float16)hv;
        const int base = slot * HSZ + (quad * 4) * PH + wl * 16 + l16;
        hbuf[base]      = hh;
        hbuf[base + PH] = (_Float16)(hv - (float)hh);
    };

    if (isP) issue_chunk(0);
    __syncthreads();                 // chunk0 drained; h zeroed
    if (isP) { convert_rows(0, 0, 8); issue_chunk(1); }
    __syncthreads();                 // xh chunk0 visible; chunk1 drained
    if (isP) { compute_xp(0); compute_xp(1); compute_xp(2); }
    __syncthreads();                 // xp[0..2] visible
    if (is0) {                       // prologue: layer0 t=0 (h=0)
        const f32x4 xp4 = *(const f32x4*)&xpl[(wl * 64 + lane) * 4];
        const float gi = sigmoid_f(xp4[0]);
        const float gg = tanh_f(xp4[2]);
        const float go = sigmoid_f(xp4[3]);
        c = gi * gg;
        store_h(h0, 0, go * tanh_f(c));
    }
    __syncthreads();

    for (int t = 0; t < 255; ++t) {
        const int s0 = t & 1, s1 = s0 ^ 1;
        const int tn = t + 1;
        if (is1) {
            f16x8 ah[2], bh[2];
            #pragma unroll
            for (int ks = 0; ks < 2; ++ks) {
                ah[ks] = *(const f16x8*)&h0[s0 * HSZ + l16 * PH + ks * 32 + k0];
                bh[ks] = *(const f16x8*)&h1[s1 * HSZ + l16 * PH + ks * 32 + k0];
            }
            f32x4 acc[4];
            #pragma unroll
            for (int g = 0; g < 4; ++g)
                acc[g] = (f32x4){gb[g], 0.f, 0.f, 0.f};
            #pragma unroll
            for (int g = 0; g < 4; ++g)
                #pragma unroll
                for (int ks = 0; ks < 2; ++ks) {
                    acc[g] = MFMA16(ah[ks], fA[g][ks], acc[g]);
                    acc[g] = MFMA16(bh[ks], fB[g][ks], acc[g]);
                }
            const float gi = sigmoid_f(acc[0][0] + acc[0][1]);
            const float gf = sigmoid_f(acc[1][0] + acc[1][1]);
            const float gg = tanh_f(acc[2][0] + acc[2][1]);
            const float go = sigmoid_f(acc[3][0] + acc[3][1]);
            c = gf * c + gi * gg;
            store_h(h1, s0, go * tanh_f(c));
        } else if (is0) {
            const f32x4 xp4 =
                *(const f32x4*)&xpl[(((tn & 3) * 4 + wl) * 64 + lane) * 4];
            f16x8 ah[2];
            #pragma unroll
            for (int ks = 0; ks < 2; ++ks)
                ah[ks] = *(const f16x8*)&h0[s0 * HSZ + l16 * PH + ks * 32 + k0];
            f32x4 acc[4];
            #pragma unroll
            for (int g = 0; g < 4; ++g)
                acc[g] = (f32x4){xp4[g], 0.f, 0.f, 0.f};
            #pragma unroll
            for (int g = 0; g < 4; ++g)
                #pragma unroll
                for (int ks = 0; ks < 2; ++ks)
                    acc[g] = MFMA16(ah[ks], fA[g][ks], acc[g]);
            const float gi = sigmoid_f(acc[0][0] + acc[0][1]);
            const float gf = sigmoid_f(acc[1][0] + acc[1][1]);
            const float gg = tanh_f(acc[2][0] + acc[2][1]);
            const float go = sigmoid_f(acc[3][0] + acc[3][1]);
            c = gf * c + gi * gg;
            store_h(h0, s1, go * tanh_f(c));
        } else {
            const int tp = t + 3;                   // produce xp 3 steps ahead
            if (tp <= 255) compute_xp(tp);
            if ((tn & 15) == 0 && tn < 240)         // issue next chunk (DMA)
                issue_chunk((tn >> 4) + 1);
            const int m16 = tn & 15;
            if (m16 >= 8 && m16 < 12 && tn < 248)   // spread strip->frag convert
                convert_rows((tn >> 4) + 1, (m16 - 8) * 2, 2);
        }
        __syncthreads();
    }

    if (is1) {   // epilogue: layer1[255] (h0 slot1, h1 slot0 -> h1 slot1)
        f16x8 ah[2], bh[2];
        #pragma unroll
        for (int ks = 0; ks < 2; ++ks) {
            ah[ks] = *(const f16x8*)&h0[HSZ + l16 * PH + ks * 32 + k0];
            bh[ks] = *(const f16x8*)&h1[l16 * PH + ks * 32 + k0];
        }
        f32x4 acc[4];
        #pragma unroll
        for (int g = 0; g < 4; ++g)
            acc[g] = (f32x4){gb[g], 0.f, 0.f, 0.f};
        #pragma unroll
        for (int g = 0; g < 4; ++g)
            #pragma unroll
            for (int ks = 0; ks < 2; ++ks) {
                acc[g] = MFMA16(ah[ks], fA[g][ks], acc[g]);
                acc[g] = MFMA16(bh[ks], fB[g][ks], acc[g]);
            }
        const float gi = sigmoid_f(acc[0][0] + acc[0][1]);
        const float gf = sigmoid_f(acc[1][0] + acc[1][1]);
        const float gg = tanh_f(acc[2][0] + acc[2][1]);
        const float go = sigmoid_f(acc[3][0] + acc[3][1]);
        c = gf * c + gi * gg;
        store_h(h1, 1, go * tanh_f(c));
    }
    __syncthreads();

    // head: rows sel*4 (hi) + sel*4+1 (lo) of slot 1; out row = bb*16+sel*4+sub
    if (tid < 512) {
        const int n   = tid & 127;
        const int sel = tid >> 7;
        float s = 0.f;
        for (int k = 0; k < 64; ++k)
            s += ((float)h1[HSZ + (sel * 4) * PH + k]
                + (float)h1[HSZ + (sel * 4 + 1) * PH + k]) * wfc[n * 64 + k];
        out[(size_t)(bb * 16 + sel * 4 + sub) * 128 + n] = s + bfc[n];
    }
}

extern "C" void kernel_launch(void* const* d_in, const int* in_sizes, int n_in,
                              void* d_out, int out_size, void* d_ws, size_t ws_size,
                              hipStream_t stream) {
    const float* x     = (const float*)d_in[0];
    const float* wih0  = (const float*)d_in[1];
    const float* whh0  = (const float*)d_in[2];
    const float* bih0  = (const float*)d_in[3];
    const float* bhh0  = (const float*)d_in[4];
    const float* wih1  = (const float*)d_in[5];
    const float* whh1  = (const float*)d_in[6];
    const float* bih1  = (const float*)d_in[7];
    const float* bhh1  = (const float*)d_in[8];
    const float* wfc   = (const float*)d_in[9];
    const float* bfc   = (const float*)d_in[10];
    float* out = (float*)d_out;

    rec_fused<<<256, 768, 0, stream>>>(x, wih0, whh0, bih0, bhh0,
                                       wih1, whh1, bih1, bhh1, wfc, bfc, out);
}